// Round 18
// baseline (197.338 us; speedup 1.0000x reference)
//
#include <hip/hip_runtime.h>
#include <hip/hip_bf16.h>
#include <math.h>

typedef short bf16x8 __attribute__((ext_vector_type(8)));
typedef float f32x4 __attribute__((ext_vector_type(4)));
typedef unsigned int u32;

#define B_DIM 8192
#define H_DIM 1024
#define NPATH 256
#define NSTEP 50

__device__ __forceinline__ void gld_lds16(const void* g, void* lds) {
  __builtin_amdgcn_global_load_lds(
      (const __attribute__((address_space(1))) u32*)g,
      (__attribute__((address_space(3))) u32*)lds, 16, 0, 0);
}

__device__ __forceinline__ void cast4(const float* in, __hip_bfloat16* out, int i) {
  float4 v = ((const float4*)in)[i];
  union { __hip_bfloat16 h[4]; short4 s; } u;
  u.h[0] = __float2bfloat16(v.x);
  u.h[1] = __float2bfloat16(v.y);
  u.h[2] = __float2bfloat16(v.z);
  u.h[3] = __float2bfloat16(v.w);
  ((short4*)out)[i] = u.s;
}

// ---------------- fused prep: pure data movement ----------------
// [0,8192) cast x ; [8192,11264) transpose W_in/W_hid/W_out ;
// [11264,11520) PLAIN cast W_agg -> waggb[256][1024] (Wc's B-operand)
__global__ __launch_bounds__(256) void prep_kernel(
    const float* __restrict__ x, const float* __restrict__ W_in,
    const float* __restrict__ W_hid, const float* __restrict__ W_out,
    const float* __restrict__ W_agg,
    __hip_bfloat16* __restrict__ xb, __hip_bfloat16* __restrict__ wtin,
    __hip_bfloat16* __restrict__ wthid, __hip_bfloat16* __restrict__ wtout,
    __hip_bfloat16* __restrict__ waggb) {
  __shared__ float t[32][33];
  int bid = blockIdx.x, tid = threadIdx.x;
  if (bid < 8192) {
    cast4(x, xb, bid * 256 + tid);
    return;
  }
  if (bid >= 11264) {
    cast4(W_agg, waggb, (bid - 11264) * 256 + tid);
    return;
  }
  int job = bid - 8192;
  const float* W; __hip_bfloat16* Wt;
  if (job < 1024)      { W = W_in;  Wt = wtin; }
  else if (job < 2048) { W = W_hid; Wt = wthid; job -= 1024; }
  else                 { W = W_out; Wt = wtout; job -= 2048; }
  int tX = job & 31, tY = job >> 5;
  int tx = tid & 31, r4 = tid >> 5;
#pragma unroll
  for (int i = 0; i < 4; ++i) {
    int ty = r4 * 4 + i;
    t[ty][tx] = W[(size_t)(tY * 32 + ty) * H_DIM + tX * 32 + tx];
  }
  __syncthreads();
#pragma unroll
  for (int i = 0; i < 4; ++i) {
    int ty = r4 * 4 + i;
    Wt[(size_t)(tX * 32 + ty) * H_DIM + tY * 32 + tx] = __float2bfloat16(t[tx][ty]);
  }
}

// ---------------- fb: fb[row] = sigmoid(h2 . W_fb + b_fb), fp32 --------------
__global__ __launch_bounds__(256) void fb_kernel(
    const __hip_bfloat16* __restrict__ h2b, const float* __restrict__ Wfb,
    const float* __restrict__ bfb, float* __restrict__ fb) {
  int wid = threadIdx.x >> 6, lane = threadIdx.x & 63;
  int row = blockIdx.x * 4 + wid;
  const __hip_bfloat16* hrow = h2b + (size_t)row * H_DIM;
  float s = 0.f;
#pragma unroll
  for (int i = lane; i < H_DIM; i += 64) s += __bfloat162float(hrow[i]) * Wfb[i];
#pragma unroll
  for (int off = 32; off > 0; off >>= 1) s += __shfl_down(s, off);
  if (lane == 0) fb[row] = 1.0f / (1.0f + expf(-(s + bfb[0])));
}

// -------- trunk stage: G8 role interleave + tail jobs (all >=4-block, audited) --
// bid < 1024: R17's group-of-8 noise/GEMM interleave (best measured structure).
// STAGE 1 extras: [1024,1040) Wc tiles (wcbt = wtout @ waggb^T, same MFMA core,
//   K=1024, 16 tiles); [1040,1072) v2 split-h blocks (32 blocks, LDS-reduced,
//   no atomics — R7's 4-block version was a 100us straggler).
// STAGE 2 extras: [1024,1028) v1[n] = DI * rowsum(wcbt[n][:]) (4 blocks, 512KB).
template <int STAGE>
__global__ __launch_bounds__(256) void stage_kernel(
    const __hip_bfloat16* __restrict__ A, const __hip_bfloat16* __restrict__ Bt,
    const float* __restrict__ bias, __hip_bfloat16* __restrict__ out,
    const float* __restrict__ noise, __hip_bfloat16* __restrict__ sb,
    int rowStart, int rowCount, float SQDT,
    const __hip_bfloat16* __restrict__ wtout, const __hip_bfloat16* __restrict__ waggb,
    __hip_bfloat16* __restrict__ wcbt,
    const float* __restrict__ W_out, const float* __restrict__ b_agg,
    const float* __restrict__ b_out, float* __restrict__ v2,
    float* __restrict__ v1, float DI) {
  __shared__ __hip_bfloat16 As[128 * 64];
  __shared__ __hip_bfloat16 Bs[128 * 64];
  const int bid = blockIdx.x;
  const int tid = threadIdx.x;

  if (STAGE == 1 && bid >= 1040) {
    // v2 split-h: block b owns cols [b*32, b*32+32), threads split h into 8 chunks
    float* red = (float*)As;  // reuse LDS as [8][32] fp32 scratch
    int b = bid - 1040;
    int dd = tid & 31, hc = tid >> 5;
    int d = b * 32 + dd;
    float s = 0.f;
#pragma unroll 8
    for (int h = hc * 128; h < hc * 128 + 128; ++h)
      s += b_agg[h] * W_out[(size_t)h * H_DIM + d];
    red[hc * 32 + dd] = s;
    __syncthreads();
    if (tid < 32) {
      float acc = b_out[b * 32 + tid];
#pragma unroll
      for (int hc2 = 0; hc2 < 8; ++hc2) acc += red[hc2 * 32 + tid];
      v2[b * 32 + tid] = acc;
    }
    return;
  }
  if (STAGE == 2 && bid >= 1024) {
    // v1[n] = DI * sum_p wcbt[n][p]  (row of 256 bf16 = 32x bf16x8, contiguous)
    int n = (bid - 1024) * 256 + tid;
    const bf16x8* row = (const bf16x8*)(wcbt + (size_t)n * NPATH);
    float s = 0.f;
#pragma unroll
    for (int q = 0; q < 32; ++q) {
      bf16x8 v = row[q];
#pragma unroll
      for (int e = 0; e < 8; ++e)
        s += __bfloat162float(*(const __hip_bfloat16*)&((const short*)&v)[e]);
    }
    v1[n] = DI * s;
    return;
  }

  // role decode (wave-uniform)
  const __hip_bfloat16 *Ap, *Btp; __hip_bfloat16* outp;
  const float* biasp; int bm, bn, N; bool relu;
  if (bid < 1024) {
    const int group = bid >> 3, l = bid & 7;
    if ((group & 1) == 0) {
      int j = (group >> 1) * 8 + l;  // 512 noise blocks, grid-stride
      for (int r = j * 256 + tid; r < rowCount; r += 512 * 256) {
        const float2* p = (const float2*)(noise + (size_t)(rowStart + r) * NSTEP);
        float s = 0.f;
#pragma unroll
        for (int i = 0; i < NSTEP / 2; ++i) { float2 v = p[i]; s += v.x + v.y; }
        sb[rowStart + r] = __float2bfloat16(SQDT * s);
      }
      return;
    }
    const int g_i = group >> 1;                  // 0..63
    bm = (g_i >> 3) * 8 + l; bn = g_i & 7;       // XCD-local A panels
    Ap = A; Btp = Bt; outp = out; biasp = bias; N = H_DIM; relu = true;
  } else {
    // Wc tile (STAGE 1): wcbt[n][p] = sum_h wtout[n][h] * waggb[p][h], K=1024
    int g = bid - 1024;                          // 16 tiles: 8 x 2
    bm = g >> 1; bn = g & 1;
    Ap = wtout; Btp = waggb; outp = wcbt; biasp = nullptr; N = NPATH; relu = false;
  }

  const int lane = tid & 63, wid = tid >> 6;
  const int wr = wid >> 1, wc = wid & 1;
  const int frow = lane & 15, kgrp = lane >> 4;

  f32x4 acc[4][4];
#pragma unroll
  for (int m = 0; m < 4; ++m)
#pragma unroll
    for (int n = 0; n < 4; ++n) acc[m][n] = (f32x4){0.f, 0.f, 0.f, 0.f};

  for (int kt = 0; kt < H_DIM; kt += 64) {
#pragma unroll
    for (int r = 0; r < 4; ++r) {
      int c = r * 256 + tid;
      int row = c >> 3, cc = c & 7;
      gld_lds16((const char*)(Ap + (size_t)(bm * 128 + row) * H_DIM + kt) + cc * 16,
                (char*)As + c * 16);
      gld_lds16((const char*)(Btp + (size_t)(bn * 128 + row) * H_DIM + kt) + cc * 16,
                (char*)Bs + c * 16);
    }
    __syncthreads();
#pragma unroll
    for (int kk = 0; kk < 64; kk += 32) {
      bf16x8 af[4], bfr[4];
#pragma unroll
      for (int m = 0; m < 4; ++m)
        af[m] = *(const bf16x8*)(As + (wr * 64 + m * 16 + frow) * 64 + kk + kgrp * 8);
#pragma unroll
      for (int n = 0; n < 4; ++n)
        bfr[n] = *(const bf16x8*)(Bs + (wc * 64 + n * 16 + frow) * 64 + kk + kgrp * 8);
#pragma unroll
      for (int m = 0; m < 4; ++m)
#pragma unroll
        for (int n = 0; n < 4; ++n)
          acc[m][n] = __builtin_amdgcn_mfma_f32_16x16x32_bf16(af[m], bfr[n], acc[m][n], 0, 0, 0);
    }
    __syncthreads();
  }

  const int r0 = bm * 128 + wr * 64;
  const int c0 = bn * 128 + wc * 64;
#pragma unroll
  for (int n = 0; n < 4; ++n) {
    int col = c0 + n * 16 + frow;
    float bv = biasp ? biasp[col] : 0.f;
#pragma unroll
    for (int m = 0; m < 4; ++m)
#pragma unroll
      for (int j = 0; j < 4; ++j) {
        int row = r0 + m * 16 + kgrp * 4 + j;
        float v = acc[m][n][j] + bv;
        if (relu) v = fmaxf(v, 0.f);
        outp[(size_t)row * N + col] = __float2bfloat16(v);
      }
  }
}

// ---------------- final: [h2|sb] @ [wtout;wcbt]^T + fb*v1 + v2 -> fp32 --------
// 256x128 tile, 8 waves, counted-vmcnt dbuf + pre-swizzled-source T2 + XCD remap.
// Dual K-source: kt<1024 reads (h2b, wtout, ld 1024); kt>=1024 (sb, wcbt, ld 256).
__global__ __launch_bounds__(512) void final_kernel(
    const __hip_bfloat16* __restrict__ A, const __hip_bfloat16* __restrict__ Bt,
    const __hip_bfloat16* __restrict__ A2, const __hip_bfloat16* __restrict__ Bt2,
    const float* __restrict__ fb, const float* __restrict__ v1,
    const float* __restrict__ v2, float* __restrict__ out) {
  constexpr int SMHALF = (256 + 128) * 64 * 2;
  __shared__ char smem[2 * SMHALF];
  const int tid = threadIdx.x;
  const int lane = tid & 63, wid = tid >> 6;
  const int wm = wid >> 2, wn = wid & 3;
  const int frow = lane & 15, kgrp = lane >> 4;
  const int gb = (blockIdx.x & 7) * 32 + (blockIdx.x >> 3);  // XCD remap (256 blocks)
  const int bm = gb >> 3, bn = gb & 7;

  auto stage = [&](int kt, int d) {
    char* dst = smem + d * SMHALF;
    const __hip_bfloat16 *As_, *Bs_;
    int alda, aldb, akt;
    if (kt < H_DIM) { As_ = A; Bs_ = Bt; alda = H_DIM; aldb = H_DIM; akt = kt; }
    else { As_ = A2; Bs_ = Bt2; alda = NPATH; aldb = NPATH; akt = kt - H_DIM; }
#pragma unroll
    for (int j = 0; j < 6; ++j) {
      int c = j * 512 + tid;
      if (j < 4) {
        int row = c >> 3, cb = (c & 7) * 16;
        int col = (cb ^ ((row & 7) << 4)) >> 1;
        gld_lds16((const void*)(As_ + (size_t)(bm * 256 + row) * alda + akt + col), dst + c * 16);
      } else {
        int cB = c - 2048;
        int row = cB >> 3, cb = (cB & 7) * 16;
        int col = (cb ^ ((row & 7) << 4)) >> 1;
        gld_lds16((const void*)(Bs_ + (size_t)(bn * 128 + row) * aldb + akt + col), dst + 32768 + cB * 16);
      }
    }
  };

  f32x4 acc[8][2];
#pragma unroll
  for (int m = 0; m < 8; ++m)
#pragma unroll
    for (int n = 0; n < 2; ++n) acc[m][n] = (f32x4){0.f, 0.f, 0.f, 0.f};

  stage(0, 0);
  const int NT = 1280 >> 6;
  for (int t = 0; t < NT; ++t) {
    const int cur = t & 1;
    if (t + 1 < NT) stage((t + 1) << 6, cur ^ 1);
    if (t + 1 >= NT) {
      asm volatile("s_waitcnt vmcnt(0)" ::: "memory");
    } else {
      asm volatile("s_waitcnt vmcnt(6)" ::: "memory");
    }
    __builtin_amdgcn_s_barrier();

    const char* Ab = smem + cur * SMHALF;
    const char* Bb = Ab + 32768;
    bf16x8 bfr[2][2];
#pragma unroll
    for (int n = 0; n < 2; ++n)
#pragma unroll
      for (int s = 0; s < 2; ++s) {
        int row = wn * 32 + n * 16 + frow;
        int cb = s * 64 + kgrp * 16;
        bfr[n][s] = *(const bf16x8*)(Bb + row * 128 + (cb ^ ((row & 7) << 4)));
      }
#pragma unroll
    for (int mh = 0; mh < 2; ++mh) {
      bf16x8 af[4][2];
#pragma unroll
      for (int m = 0; m < 4; ++m)
#pragma unroll
        for (int s = 0; s < 2; ++s) {
          int row = wm * 128 + (mh * 4 + m) * 16 + frow;
          int cb = s * 64 + kgrp * 16;
          af[m][s] = *(const bf16x8*)(Ab + row * 128 + (cb ^ ((row & 7) << 4)));
        }
#pragma unroll
      for (int m = 0; m < 4; ++m)
#pragma unroll
        for (int n = 0; n < 2; ++n)
#pragma unroll
          for (int s = 0; s < 2; ++s)
            acc[mh * 4 + m][n] = __builtin_amdgcn_mfma_f32_16x16x32_bf16(
                af[m][s], bfr[n][s], acc[mh * 4 + m][n], 0, 0, 0);
    }
    __builtin_amdgcn_s_barrier();
  }

  const int r0 = bm * 256 + wm * 128;
  const int c0 = bn * 128 + wn * 32;
#pragma unroll
  for (int n = 0; n < 2; ++n) {
    int col = c0 + n * 16 + frow;
    float v1c = v1[col], v2c = v2[col];
#pragma unroll
    for (int m = 0; m < 8; ++m)
#pragma unroll
      for (int j = 0; j < 4; ++j) {
        int row = r0 + m * 16 + kgrp * 4 + j;
        out[(size_t)row * H_DIM + col] = acc[m][n][j] + fb[row] * v1c + v2c;
      }
  }
}

extern "C" void kernel_launch(void* const* d_in, const int* in_sizes, int n_in,
                              void* d_out, int out_size, void* d_ws, size_t ws_size,
                              hipStream_t stream) {
  (void)in_sizes; (void)n_in; (void)out_size; (void)ws_size;
  const float* x     = (const float*)d_in[0];
  const float* W_in  = (const float*)d_in[1];
  const float* b_in  = (const float*)d_in[2];
  const float* W_hid = (const float*)d_in[3];
  const float* b_hid = (const float*)d_in[4];
  const float* W_fb  = (const float*)d_in[5];
  const float* b_fb  = (const float*)d_in[6];
  const float* W_agg = (const float*)d_in[7];
  const float* b_agg = (const float*)d_in[8];
  const float* W_out = (const float*)d_in[9];
  const float* b_out = (const float*)d_in[10];
  const float* noise = (const float*)d_in[11];

  const int B = B_DIM, H = H_DIM, P = NPATH;
  const int R = B * P;

  size_t off = 0;
  char* base = (char*)d_ws;
  auto take = [&](size_t bytes) -> char* {
    char* r = base + off;
    off = (off + bytes + 255) & ~(size_t)255;
    return r;
  };
  __hip_bfloat16* xb    = (__hip_bfloat16*)take((size_t)B * H * 2);
  __hip_bfloat16* h1b   = (__hip_bfloat16*)take((size_t)B * H * 2);
  __hip_bfloat16* h2b   = (__hip_bfloat16*)take((size_t)B * H * 2);
  __hip_bfloat16* wtin  = (__hip_bfloat16*)take((size_t)H * H * 2);
  __hip_bfloat16* wthid = (__hip_bfloat16*)take((size_t)H * H * 2);
  __hip_bfloat16* wtout = (__hip_bfloat16*)take((size_t)H * H * 2);
  __hip_bfloat16* waggb = (__hip_bfloat16*)take((size_t)P * H * 2);
  __hip_bfloat16* wcbt  = (__hip_bfloat16*)take((size_t)H * P * 2);
  __hip_bfloat16* sb    = (__hip_bfloat16*)take((size_t)R * 2);
  float* fb = (float*)take((size_t)B * 4);
  float* v1 = (float*)take((size_t)H * 4);
  float* v2 = (float*)take((size_t)H * 4);

  float dt = 1.0f / NSTEP;
  float DI = 0.f;
  for (int j = 0; j < NSTEP; ++j) DI += expf(-0.1f * ((float)j * dt));
  DI *= dt;
  float SQDT = sqrtf(dt);

  prep_kernel<<<11520, 256, 0, stream>>>(x, W_in, W_hid, W_out, W_agg,
                                         xb, wtin, wthid, wtout, waggb);
  // stage1: trunk x@W_in + noise half 1 + Wc tiles (16) + v2 split-h (32)
  stage_kernel<1><<<1072, 256, 0, stream>>>(
      xb, wtin, b_in, h1b, noise, sb, 0, R / 2, SQDT,
      wtout, waggb, wcbt, W_out, b_agg, b_out, v2, v1, DI);
  // stage2: trunk h1@W_hid + noise half 2 + v1 rowsum (4)
  stage_kernel<2><<<1028, 256, 0, stream>>>(
      h1b, wthid, b_hid, h2b, noise, sb, R / 2, R - R / 2, SQDT,
      wtout, waggb, wcbt, W_out, b_agg, b_out, v2, v1, DI);
  fb_kernel<<<B / 4, 256, 0, stream>>>(h2b, W_fb, b_fb, fb);
  // final: [h2|sb] @ [wtout;wcbt]^T + fb*v1 + v2 -> fp32, K=1280 dual-source
  final_kernel<<<256, 512, 0, stream>>>(h2b, wtout, sb, wcbt, fb, v1, v2, (float*)d_out);
}